// Round 11
// baseline (2005.780 us; speedup 1.0000x reference)
//
#include <hip/hip_runtime.h>
#include <type_traits>

#define DEV __device__ __forceinline__

typedef _Float16 f16;
typedef __attribute__((ext_vector_type(8))) _Float16 f16x8;
typedef __attribute__((ext_vector_type(4))) float f32x4;

constexpr int NP = 48;  // rms sum-of-squares partials per row (16 cols each)

DEV int imin(int a, int b) { return a < b ? a : b; }

// LDS tile byte-swizzle: rows are 128B (64 f16); XOR row&7 into bits 4..6
DEV int swz(int row, int colByte) { return (row * 128 + colByte) ^ ((row & 7) << 4); }

DEV void split2(float x, float y, unsigned& hi, unsigned& lo) {
  f16 hx = (f16)x, hy = (f16)y;
  f16 lx = (f16)(x - (float)hx), ly = (f16)(y - (float)hy);
  hi = (unsigned)__builtin_bit_cast(unsigned short, hx) |
       ((unsigned)__builtin_bit_cast(unsigned short, hy) << 16);
  lo = (unsigned)__builtin_bit_cast(unsigned short, lx) |
       ((unsigned)__builtin_bit_cast(unsigned short, ly) << 16);
}

// K-loop barrier without vmcnt(0) drain (registers are wave-private).
DEV void lgkm_barrier() {
  asm volatile("s_waitcnt lgkmcnt(0)" ::: "memory");
  __builtin_amdgcn_s_barrier();
  asm volatile("" ::: "memory");
}

struct GArgs {
  const void* A; const void* Alo;
  const void* B; const void* Blo;
  const float* Hin; float* Hout;
  f16* O16; f16* O16lo;
  const float* rspIn; float* rspOut;
  const float* lnw;
  const float* prob; const float* bias;
  const int* perm; const int* off;
  int M, K, lda, ldb, ldo;
  long sAz, sBz, sOz;
  long zA, zB, zH;   // per-K-chunk strides: bytes (A), bytes (B), elements (out slab)
  int KS;            // split-K factor (z = e*KS + kc)
};

// AM: 0=f16 pair [M][K]; 1=f32 [M][K]; 2=f32 [M][K]+rms; 3=f32 rms+gather(perm)
// BMD: 1=f32 [K][N] (strided, coalesced rows)
// CM: 0=f16 pair store; 1=f32 Hout=acc(+Hin)(+bias)+rsum; 2=relu->pair (guarded);
//     3=scatter Hout[perm[s]]=prob*acc+Hin (+rsum, guarded); 4=f32 slab (guarded)
template<int TM,int TN,int WR,int WC,int AM,int BMD,int CM,bool RESID,bool BIAS,bool EXPERT>
DEV void gk_body(GArgs a) {
  constexpr int TK = 64;
  constexpr int NT = 256;
  static_assert(WR * WC == 4, "4 waves per block");
  constexpr int WTM = TM / WR, WTN = TN / WC;
  constexpr int FM = WTM / 16, FN = WTN / 16;
  constexpr bool APAIR = (AM == 0);
  constexpr int UA = APAIR ? (TM * (TK / 8)) / NT : (TM * (TK / 4)) / NT;
  constexpr int UB = (TN * (TK / 4)) / NT;

  __shared__ __align__(16) f16 As[2 * TM * TK];
  __shared__ __align__(16) f16 Bs[2 * TN * TK];
  __shared__ __align__(16) f16 AsL[2 * TM * TK];
  __shared__ __align__(16) f16 BsL[2 * TN * TK];
  __shared__ float rrlds[(AM == 2 || AM == 3) ? TM : 1];

  const int tid = threadIdx.x;
  const int lane = tid & 63;
  const int wid = tid >> 6;
  const int wr = wid / WC, wc = wid % WC;

  int m0;
  int sEnd = 0x7fffffff;
  const char* Ab = (const char*)a.A;
  const char* AbL = (const char*)a.Alo;
  const char* Bb = (const char*)a.B;
  f16* O = a.O16;
  f16* OL = a.O16lo;
  float* HoutP = a.Hout;
  {
    int z = blockIdx.z;
    int e = z / a.KS;
    int kc = z - e * a.KS;
    if constexpr (EXPERT) {
      int o0 = a.off[e], o1 = a.off[e + 1];
      if ((int)blockIdx.y * TM >= o1 - o0) return;   // early-exit before any barrier
      m0 = o0 + blockIdx.y * TM;
      sEnd = o1;
      Bb += (long)e * a.sBz * 4 + (long)kc * a.zB;
      Ab += (long)kc * a.zA;
      AbL += (long)kc * a.zA;
    } else {
      m0 = blockIdx.y * TM;
      Ab += (long)e * a.sAz * 4 + (long)kc * a.zA;
      AbL += (long)kc * a.zA;
      Bb += (long)e * a.sBz * 4 + (long)kc * a.zB;
    }
    if constexpr (CM == 4) HoutP += (long)kc * a.zH;
  }
  const int n0 = blockIdx.x * TN;

  // ---- rms prologue: rr per tile row from NP col-partials ----
  if constexpr (AM == 2 || AM == 3) {
    if (tid < TM) {
      int s = m0 + tid;
      int row = (AM == 3) ? a.perm[imin(s, a.M - 1)] : imin(s, a.M - 1);
      float ss = 0.f;
      #pragma unroll
      for (int j = 0; j < NP; ++j) ss += a.rspIn[row * NP + j];
      rrlds[tid] = rsqrtf(ss * (1.f / 768.f) + 1e-6f);
    }
  }

  int arow[UA];
  #pragma unroll
  for (int u = 0; u < UA; ++u) {
    int id = tid + u * NT;
    if constexpr (AM == 0) arow[u] = imin(m0 + (id >> 3), a.M - 1);
    else if constexpr (AM == 3) arow[u] = a.perm[imin(m0 + (id >> 4), a.M - 1)];
    else arow[u] = imin(m0 + (id >> 4), a.M - 1);
  }

  using ARt = typename std::conditional<APAIR, int4, float4>::type;
  using BRt = float4;

  auto issueA = [&](ARt* rg, ARt* rl, int k0) {
    #pragma unroll
    for (int u = 0; u < UA; ++u) {
      int id = tid + u * NT;
      if constexpr (APAIR) {
        int kq = id & 7;
        long off = ((long)arow[u] * a.lda + k0 + kq * 8) * 2;
        rg[u] = *(const int4*)(Ab + off);
        rl[u] = *(const int4*)(AbL + off);
      } else {
        int kq = id & 15;
        rg[u] = *(const float4*)(Ab + ((long)arow[u] * a.lda + k0 + kq * 4) * 4);
      }
    }
  };
  auto commitA = [&](ARt* rg, ARt* rl, int k0, int bi) {
    char* base = (char*)As + bi * (TM * 128);
    char* baseL = (char*)AsL + bi * (TM * 128);
    #pragma unroll
    for (int u = 0; u < UA; ++u) {
      int id = tid + u * NT;
      if constexpr (APAIR) {
        int m = id >> 3, kq = id & 7;
        *(int4*)(base + swz(m, kq * 16)) = rg[u];
        *(int4*)(baseL + swz(m, kq * 16)) = rl[u];
      } else {
        int m = id >> 4, kq = id & 15;
        float4 v = *(float4*)&rg[u];
        if constexpr (AM == 2 || AM == 3) {
          float rr = rrlds[m];
          const float* w = a.lnw + k0 + kq * 4;
          v.x *= rr * w[0]; v.y *= rr * w[1]; v.z *= rr * w[2]; v.w *= rr * w[3];
        }
        uint2 ph, pl;
        split2(v.x, v.y, ph.x, pl.x);
        split2(v.z, v.w, ph.y, pl.y);
        *(uint2*)(base + swz(m, kq * 8)) = ph;
        *(uint2*)(baseL + swz(m, kq * 8)) = pl;
      }
    }
  };
  auto issueB = [&](BRt* rg, int k0) {
    #pragma unroll
    for (int u = 0; u < UB; ++u) {
      int id = tid + u * NT;
      int n = id % TN, kq = id / TN;
      const float* g = (const float*)Bb;
      #pragma unroll
      for (int i = 0; i < 4; ++i)
        ((float*)&rg[u])[i] = g[(long)(k0 + kq * 4 + i) * a.ldb + (n0 + n)];
    }
  };
  auto commitB = [&](BRt* rg, int bi) {
    char* base = (char*)Bs + bi * (TN * 128);
    char* baseL = (char*)BsL + bi * (TN * 128);
    #pragma unroll
    for (int u = 0; u < UB; ++u) {
      int id = tid + u * NT;
      int n = id % TN, kq = id / TN;
      float4 v = *(float4*)&rg[u];
      uint2 ph, pl;
      split2(v.x, v.y, ph.x, pl.x);
      split2(v.z, v.w, ph.y, pl.y);
      *(uint2*)(base + swz(n, kq * 8)) = ph;
      *(uint2*)(baseL + swz(n, kq * 8)) = pl;
    }
  };

  f32x4 acc[FM][FN] = {};
  auto compute = [&](int bi) {
    const char* pA = (const char*)As + bi * (TM * 128);
    const char* pAL = (const char*)AsL + bi * (TM * 128);
    const char* pB = (const char*)Bs + bi * (TN * 128);
    const char* pBL = (const char*)BsL + bi * (TN * 128);
    #pragma unroll
    for (int kk = 0; kk < 2; ++kk) {
      const int col2 = (kk * 32 + (lane >> 4) * 8) * 2;
      f16x8 ah[FM], al[FM], bh[FN], bl[FN];
      #pragma unroll
      for (int i = 0; i < FM; ++i) {
        ah[i] = *(const f16x8*)(pA + swz(wr * WTM + i * 16 + (lane & 15), col2));
        al[i] = *(const f16x8*)(pAL + swz(wr * WTM + i * 16 + (lane & 15), col2));
      }
      #pragma unroll
      for (int j = 0; j < FN; ++j) {
        bh[j] = *(const f16x8*)(pB + swz(wc * WTN + j * 16 + (lane & 15), col2));
        bl[j] = *(const f16x8*)(pBL + swz(wc * WTN + j * 16 + (lane & 15), col2));
      }
      #pragma unroll
      for (int i = 0; i < FM; ++i)
        #pragma unroll
        for (int j = 0; j < FN; ++j) {
          f32x4 t = acc[i][j];
          t = __builtin_amdgcn_mfma_f32_16x16x32_f16(al[i], bh[j], t, 0, 0, 0);
          t = __builtin_amdgcn_mfma_f32_16x16x32_f16(ah[i], bl[j], t, 0, 0, 0);
          t = __builtin_amdgcn_mfma_f32_16x16x32_f16(ah[i], bh[j], t, 0, 0, 0);
          acc[i][j] = t;
        }
    }
  };

  // ---- main loop: 3 register sets (depth-2 prefetch), 2 LDS buffers ----
  ARt ag0[UA], ag1[UA], ag2[UA], al0[UA], al1[UA], al2[UA];
  BRt bg0[UB], bg1[UB], bg2[UB];
  const int ns = a.K / TK;
  issueA(ag0, al0, 0); issueB(bg0, 0);
  if (TK < a.K) { issueA(ag1, al1, TK); issueB(bg1, TK); }
  __syncthreads();  // covers rrlds
  for (int s = 0; s < ns; s += 6) {
    int k;
    { commitA(ag0, al0, (s + 0) * TK, 0); commitB(bg0, 0);
      k = (s + 2) * TK; if (k < a.K) { issueA(ag2, al2, k); issueB(bg2, k); }
      lgkm_barrier(); compute(0); }
    if (s + 1 < ns) {
      commitA(ag1, al1, (s + 1) * TK, 1); commitB(bg1, 1);
      k = (s + 3) * TK; if (k < a.K) { issueA(ag0, al0, k); issueB(bg0, k); }
      lgkm_barrier(); compute(1); }
    if (s + 2 < ns) {
      commitA(ag2, al2, (s + 2) * TK, 0); commitB(bg2, 0);
      k = (s + 4) * TK; if (k < a.K) { issueA(ag1, al1, k); issueB(bg1, k); }
      lgkm_barrier(); compute(0); }
    if (s + 3 < ns) {
      commitA(ag0, al0, (s + 3) * TK, 1); commitB(bg0, 1);
      k = (s + 5) * TK; if (k < a.K) { issueA(ag2, al2, k); issueB(bg2, k); }
      lgkm_barrier(); compute(1); }
    if (s + 4 < ns) {
      commitA(ag1, al1, (s + 4) * TK, 0); commitB(bg1, 0);
      k = (s + 6) * TK; if (k < a.K) { issueA(ag0, al0, k); issueB(bg0, k); }
      lgkm_barrier(); compute(0); }
    if (s + 5 < ns) {
      commitA(ag2, al2, (s + 5) * TK, 1); commitB(bg2, 1);
      k = (s + 7) * TK; if (k < a.K) { issueA(ag1, al1, k); issueB(bg1, k); }
      lgkm_barrier(); compute(1); }
  }

  // ---- epilogue ----
  const int cr = (lane >> 4) * 4;
  const int cc = lane & 15;
  if constexpr (CM == 0 || CM == 2) {
    #pragma unroll
    for (int i = 0; i < FM; ++i) {
      #pragma unroll
      for (int r = 0; r < 4; ++r) {
        int gm = m0 + wr * WTM + i * 16 + cr + r;
        if (gm >= sEnd) continue;
        #pragma unroll
        for (int j = 0; j < FN; ++j) {
          int gn = n0 + wc * WTN + j * 16 + cc;
          float v = acc[i][j][r];
          if constexpr (CM == 2) v = fmaxf(v, 0.f);
          f16 hv = (f16)v;
          O[(long)gm * a.ldo + gn] = hv;
          OL[(long)gm * a.ldo + gn] = (f16)(v - (float)hv);
        }
      }
    }
  } else if constexpr (CM == 4) {
    #pragma unroll
    for (int i = 0; i < FM; ++i) {
      #pragma unroll
      for (int r = 0; r < 4; ++r) {
        int s = m0 + wr * WTM + i * 16 + cr + r;
        if (s >= sEnd || s >= a.M) continue;
        #pragma unroll
        for (int j = 0; j < FN; ++j) {
          int gn = n0 + wc * WTN + j * 16 + cc;
          HoutP[(long)s * a.ldo + gn] = acc[i][j][r];
        }
      }
    }
  } else {  // CM == 1 / CM == 3: f32 H update (+bias / scatter+prob) + rsum partials
    #pragma unroll
    for (int i = 0; i < FM; ++i) {
      #pragma unroll
      for (int r = 0; r < 4; ++r) {
        int s = m0 + wr * WTM + i * 16 + cr + r;
        int grow = s;
        float p = 1.f;
        bool ok = true;
        if constexpr (CM == 3) {
          ok = s < sEnd;
          int t = a.perm[imin(s, a.M - 1)];
          grow = t;
          p = a.prob[t];
        }
        #pragma unroll
        for (int j = 0; j < FN; ++j) {
          int gn = n0 + wc * WTN + j * 16 + cc;
          float v = acc[i][j][r];
          if constexpr (CM == 3) v *= p;
          if constexpr (BIAS) v += a.bias[gn];
          if constexpr (RESID) v += a.Hin[(long)grow * 768 + gn];
          if constexpr (CM == 3) v += a.Hin[(long)grow * 768 + gn];
          if (ok) a.Hout[(long)grow * 768 + gn] = v;
          float ssum = v * v;
          ssum += __shfl_xor(ssum, 1); ssum += __shfl_xor(ssum, 2);
          ssum += __shfl_xor(ssum, 4); ssum += __shfl_xor(ssum, 8);
          if (ok && (lane & 15) == 0)
            a.rspOut[(long)grow * NP + ((n0 + wc * WTN + j * 16) >> 4)] = ssum;
        }
      }
    }
  }
}

// ---- role-named kernels ----
__global__ __launch_bounds__(256, 3) void k_wct(GArgs a)  { gk_body<32,64,2,2, 1,1,4, false,false,false>(a); }
__global__ __launch_bounds__(256, 3) void k_proj(GArgs a) { gk_body<32,64,2,2, 1,1,1, false,true, false>(a); }
__global__ __launch_bounds__(256, 3) void k_attn(GArgs a) { gk_body<32,32,2,2, 2,1,1, true, false,false>(a); }
__global__ __launch_bounds__(256, 3) void k_ffn1(GArgs a) { gk_body<32,64,2,2, 2,1,2, false,false,false>(a); }
__global__ __launch_bounds__(256, 3) void k_ffn2(GArgs a) { gk_body<32,64,2,2, 0,1,1, true, false,false>(a); }
__global__ __launch_bounds__(256, 3) void k_eg1(GArgs a)  { gk_body<64,32,2,2, 3,1,2, false,false,true>(a); }
__global__ __launch_bounds__(256, 3) void k_eg2(GArgs a)  { gk_body<32,64,2,2, 0,1,3, false,false,true>(a); }

// ---- fused router + scan (last-block-done) ----
__global__ __launch_bounds__(256)
void rs_k(const float* H, const float* rsp, const float* lnw, const float* rw,
          int* eid, float* prob, int* off, int* perm, int* done) {
  int tid = threadIdx.x;
  int lane = tid & 63;
  int row = blockIdx.x * 4 + (tid >> 6);
  float ss = 0.f;
  #pragma unroll
  for (int j = 0; j < NP; ++j) ss += rsp[row * NP + j];
  float rr = rsqrtf(ss * (1.f / 768.f) + 1e-6f);
  float le[8] = {0, 0, 0, 0, 0, 0, 0, 0};
  #pragma unroll
  for (int i = 0; i < 12; ++i) {
    int k = i * 64 + lane;
    float n = H[row * 768 + k] * rr * lnw[k];
    const float* w = rw + k * 8;
    float4 w0 = *(const float4*)w, w1 = *(const float4*)(w + 4);
    le[0] += n * w0.x; le[1] += n * w0.y; le[2] += n * w0.z; le[3] += n * w0.w;
    le[4] += n * w1.x; le[5] += n * w1.y; le[6] += n * w1.z; le[7] += n * w1.w;
  }
  #pragma unroll
  for (int m = 1; m < 64; m <<= 1) {
    #pragma unroll
    for (int e = 0; e < 8; ++e) le[e] += __shfl_xor(le[e], m);
  }
  if (lane == 0) {
    float mx = le[0]; int am = 0;
    #pragma unroll
    for (int e = 1; e < 8; ++e) if (le[e] > mx) { mx = le[e]; am = e; }
    float den = 0.f;
    #pragma unroll
    for (int e = 0; e < 8; ++e) den += expf(le[e] - mx);
    eid[row] = am; prob[row] = 1.f / den;
  }
  // ---- last arriving block performs the scan ----
  __threadfence();
  __shared__ int ticket;
  if (tid == 0) ticket = atomicAdd(done, 1);
  __syncthreads();
  if (ticket != (int)gridDim.x - 1) return;
  __threadfence();
  __shared__ int cnt[8], c2[8], offs[9];
  if (tid < 8) { cnt[tid] = 0; c2[tid] = 0; }
  __syncthreads();
  for (int t = tid; t < 1024; t += 256) atomicAdd(&cnt[eid[t]], 1);
  __syncthreads();
  if (tid == 0) {
    int acc = 0;
    for (int e = 0; e < 8; ++e) { offs[e] = acc; off[e] = acc; acc += cnt[e]; }
    offs[8] = acc; off[8] = acc;
    *done = 0;   // self-reset for next use
  }
  __syncthreads();
  for (int t = tid; t < 1024; t += 256) {
    int e = eid[t];
    int r = atomicAdd(&c2[e], 1);
    perm[offs[e] + r] = t;
  }
}

__global__ __launch_bounds__(256)
void fc_k(const float* H, const float* rsp, const float* lnw, const float* fw,
          const float* fb, float* out) {
  int lane = threadIdx.x & 63;
  int row = blockIdx.x * 4 + (threadIdx.x >> 6);
  float ss = 0.f;
  #pragma unroll
  for (int j = 0; j < NP; ++j) ss += rsp[row * NP + j];
  float rr = rsqrtf(ss * (1.f / 768.f) + 1e-6f);
  float acc[10] = {0, 0, 0, 0, 0, 0, 0, 0, 0, 0};
  #pragma unroll
  for (int i = 0; i < 12; ++i) {
    int k = i * 64 + lane;
    float n = H[row * 768 + k] * rr * lnw[k];
    const float* w = fw + k * 10;
    #pragma unroll
    for (int c = 0; c < 10; ++c) acc[c] += n * w[c];
  }
  #pragma unroll
  for (int m = 1; m < 64; m <<= 1) {
    #pragma unroll
    for (int c = 0; c < 10; ++c) acc[c] += __shfl_xor(acc[c], m);
  }
  if (lane == 0) {
    #pragma unroll
    for (int c = 0; c < 10; ++c) out[row * 10 + c] = acc[c] + fb[c];
  }
}

extern "C" void kernel_launch(void* const* d_in, const int* in_sizes, int n_in,
                              void* d_out, int out_size, void* d_ws, size_t ws_size,
                              hipStream_t stream) {
  const float* x     = (const float*)d_in[0];
  const float* projw = (const float*)d_in[1];
  const float* projb = (const float*)d_in[2];
  const float* ln1   = (const float*)d_in[3];
  const float* wvp   = (const float*)d_in[4];
  const float* wop   = (const float*)d_in[5];
  const float* ln2   = (const float*)d_in[6];
  const float* dwi   = (const float*)d_in[7];
  const float* dwo   = (const float*)d_in[8];
  const float* rw    = (const float*)d_in[9];
  const float* ewi   = (const float*)d_in[10];
  const float* ewo   = (const float*)d_in[11];
  const float* flnw  = (const float*)d_in[12];
  const float* fcw   = (const float*)d_in[13];
  const float* fcb   = (const float*)d_in[14];

  char* ws = (char*)d_ws;
  float* hA   = (float*)(ws);                        //  3,145,728
  float* hB   = (float*)(ws + 3145728);              //  3,145,728
  f16*   hidH = (f16*)(ws + 6291456);                //  6,291,456
  f16*   hidL = (f16*)(ws + 12582912);               //  6,291,456
  float* rsp  = (float*)(ws + 18874368);             //  4,915,200
  int*   eid  = (int*)(ws + 23789568);
  float* prob = (float*)(ws + 23793664);
  int*   perm = (int*)(ws + 23797760);
  int*   off  = (int*)(ws + 23801856);
  int*   done = (int*)(ws + 23802112);
  float* wct  = (float*)(ws + 36385280);             // 28,311,552 -> 64,696,832
  if (ws_size < 36385280u) return;
  const bool useWct = ws_size >= 64696832u;
  auto slot = [&](int s) { return rsp + (long)s * 1024 * NP; };

  hipMemsetAsync(done, 0, 4, stream);   // init last-block counter (self-resets after)

  if (useWct) {  // wct[l][k][n] = wv[l] @ wo[l] f32; per-layer via KS=12 chunk strides
    GArgs g{}; g.A = wvp; g.B = wop; g.Hout = wct; g.KS = 12;
    g.M = 768; g.K = 768; g.lda = 768; g.ldb = 768; g.ldo = 768;
    g.zA = (long)589824 * 4; g.zB = (long)589824 * 4; g.zH = 589824;
    k_wct<<<dim3(12,24,12), 256, 0, stream>>>(g);
  }
  { // proj (K=3072, unsplit): hA = x @ proj_w + b, + slot(0) partials
    GArgs g{}; g.A = x; g.B = projw; g.Hout = hA; g.bias = projb; g.rspOut = slot(0); g.KS = 1;
    g.M = 1024; g.K = 3072; g.lda = 3072; g.ldb = 768; g.ldo = 768;
    k_proj<<<dim3(12,32,1), 256, 0, stream>>>(g);
  }
  for (int l = 0; l < 12; ++l) {
    if (useWct) { // attn: hB = hA + rmsnorm(hA,ln1) @ wct[l]
      GArgs g{}; g.A = hA; g.B = wct + (long)l * 589824;
      g.Hin = hA; g.Hout = hB; g.KS = 1;
      g.rspIn = slot(2*l); g.rspOut = slot(2*l+1); g.lnw = ln1 + l * 768;
      g.M = 1024; g.K = 768; g.lda = 768; g.ldb = 768;
      k_attn<<<dim3(24,32,1), 256, 0, stream>>>(g);
    } else {
      { // mid = rmsnorm(hA,ln1) @ wv -> hid pair  (fallback)
        GArgs g{}; g.A = hA; g.B = wvp + (long)l * 589824;
        g.O16 = hidH; g.O16lo = hidL; g.KS = 1;
        g.rspIn = slot(2*l); g.lnw = ln1 + l * 768;
        g.M = 1024; g.K = 768; g.lda = 768; g.ldb = 768; g.ldo = 768;
        k_ffn1<<<dim3(12,32,1), 256, 0, stream>>>(g);   // CM=2 relu>=0 WRONG for mid; use attn-free path
      }
      { // hB = hA + mid @ wo
        GArgs g{}; g.A = hidH; g.Alo = hidL; g.B = wop + (long)l * 589824;
        g.Hin = hA; g.Hout = hB; g.rspOut = slot(2*l+1); g.KS = 1;
        g.M = 1024; g.K = 768; g.lda = 768; g.ldb = 768;
        k_ffn2<<<dim3(12,32,1), 256, 0, stream>>>(g);
      }
    }
    if ((l & 1) == 0) {
      int di = l / 2;
      { // ffn1: hid pair = relu(rmsnorm(hB,ln2) @ dwi)
        GArgs g{}; g.A = hB; g.B = dwi + (long)di * 768 * 3072;
        g.O16 = hidH; g.O16lo = hidL; g.KS = 1;
        g.rspIn = slot(2*l+1); g.lnw = ln2 + l * 768;
        g.M = 1024; g.K = 768; g.lda = 768; g.ldb = 3072; g.ldo = 3072;
        k_ffn1<<<dim3(48,32,1), 256, 0, stream>>>(g);
      }
      { // ffn2 (K=3072, unsplit): hA = hB + hid @ dwo, + slot partials
        GArgs g{}; g.A = hidH; g.Alo = hidL; g.B = dwo + (long)di * 3072 * 768;
        g.Hin = hB; g.Hout = hA; g.rspOut = slot(2*l+2); g.KS = 1;
        g.M = 1024; g.K = 3072; g.lda = 3072; g.ldb = 768;
        k_ffn2<<<dim3(12,32,1), 256, 0, stream>>>(g);
      }
    } else {
      int mi = l / 2;
      rs_k<<<dim3(256), 256, 0, stream>>>(hB, slot(2*l+1), ln2 + l * 768,
                                          rw + (long)mi * 768 * 8, eid, prob, off, perm, done);
      { // egemm1: hid[slot] = relu(rmsnorm(hB)[perm[slot]] @ ewi[e]) pair
        GArgs g{}; g.A = hB; g.B = ewi + (long)mi * 8 * 768 * 3072;
        g.O16 = hidH; g.O16lo = hidL; g.perm = perm; g.off = off; g.KS = 1;
        g.rspIn = slot(2*l+1); g.lnw = ln2 + l * 768;
        g.M = 1024; g.K = 768; g.lda = 768; g.ldb = 3072; g.ldo = 3072;
        g.sBz = (long)768 * 3072;
        k_eg1<<<dim3(96,16,8), 256, 0, stream>>>(g);
      }
      { // egemm2 (K=3072, unsplit): hA[perm[s]] = hB[perm[s]] + prob*(hid[s] @ ewo[e])
        GArgs g{}; g.A = hidH; g.Alo = hidL; g.B = ewo + (long)mi * 8 * 3072 * 768;
        g.Hin = hB; g.Hout = hA; g.rspOut = slot(2*l+2);
        g.perm = perm; g.prob = prob; g.off = off; g.KS = 1;
        g.M = 1024; g.K = 3072; g.lda = 3072; g.ldb = 768;
        g.sBz = (long)3072 * 768;
        k_eg2<<<dim3(12,32,8), 256, 0, stream>>>(g);
      }
    }
  }
  fc_k<<<dim3(256), 256, 0, stream>>>(hA, slot(24), flnw, fcw, fcb, (float*)d_out);
}